// Round 2
// 197.089 us; speedup vs baseline: 1.0477x; 1.0477x over previous
//
#include <hip/hip_runtime.h>
#include <stdint.h>

#define HH 2048
#define WW 2048
#define HW (HH * WW)
#define N4 (HW / 4)
#define FB 512    // fine histogram bins over fixed [0,1)
#define G1 512    // hist blocks, 1024 threads: 512*1024*2 == N4 (exactly 2 iters/thread)
#define G3 512    // main blocks, 1024 threads: 4-row tile/block, 2 rows/thread

// ws uint32 layout — 519 words = 2076 B (PROVEN-SAFE; 17.4 KB faulted in round 4):
// [0..511]   fine hist; AFTER cdf_k: [0..255] = cdf (float), [256]=gmin (float), [257]=gmax (float)
// [512..517] acc floats: 0=recon_low 1=recon_eq 2=sum|dRg| 3=sumRg 4=sum|dL|e^-10|dRg| 5=sum L*e^-10Rg
// [518]      done counter

__device__ __forceinline__ float gray_pil(float r, float g, float b) {
    float qr = floorf(fminf(fmaxf(r, 0.f), 1.f) * 255.f);
    float qg = floorf(fminf(fmaxf(g, 0.f), 1.f) * 255.f);
    float qb = floorf(fminf(fmaxf(b, 0.f), 1.f) * 255.f);
    // all terms integers < 2^24: exact in fp32
    float s = floorf((qr * 19595.f + qg * 38470.f + qb * 7471.f + 32768.f) * (1.f / 65536.f));
    return s * (1.f / 255.f);
}

// ---------------- K1: fixed-range fine histogram of per-pixel channel max ----------------
// Full static occupancy target: 512 blocks x 16 waves; launch_bounds(1024,4) = no-spill VGPR cap.
__global__ __launch_bounds__(1024, 4) void hist_k(const float* __restrict__ im, uint32_t* __restrict__ ctl) {
    __shared__ uint32_t lh[FB];
    int t = threadIdx.x;
    if (t < FB) lh[t] = 0u;
    __syncthreads();

    const float4* im4 = (const float4*)im;
    int tid = blockIdx.x * 1024 + t;
#pragma unroll
    for (int k = 0; k < 2; ++k) {            // N4 == G1*1024*2 exactly
        int i = tid + k * (G1 * 1024);
        float4 a = im4[i], b = im4[i + N4], c = im4[i + 2 * N4];
        float m[4];
        m[0] = fmaxf(a.x, fmaxf(b.x, c.x));
        m[1] = fmaxf(a.y, fmaxf(b.y, c.y));
        m[2] = fmaxf(a.z, fmaxf(b.z, c.z));
        m[3] = fmaxf(a.w, fmaxf(b.w, c.w));
#pragma unroll
        for (int j = 0; j < 4; ++j) {
            int bin = (int)(m[j] * (float)FB);
            bin = bin < 0 ? 0 : (bin > FB - 1 ? FB - 1 : bin);
            atomicAdd(&lh[bin], 1u);
        }
    }
    __syncthreads();
    if (t < FB && lh[t]) atomicAdd(&ctl[t], lh[t]);
}

// ---------------- K2: tiny single-block cdf derivation (unchanged, proven numerics) ----------------
__global__ __launch_bounds__(256) void cdf_k(uint32_t* __restrict__ ctl) {
    __shared__ uint32_t sf[FB];
    __shared__ uint32_t sc[256];
    __shared__ uint32_t smm[2];
    int t = threadIdx.x;
    sf[t] = ctl[t];
    sf[t + 256] = ctl[t + 256];
    sc[t] = 0u;
    if (t == 0) { smm[0] = FB; smm[1] = 0u; }
    __syncthreads();
    if (sf[t]) { atomicMin(&smm[0], (uint32_t)t); atomicMax(&smm[1], (uint32_t)t); }
    if (sf[t + 256]) { atomicMin(&smm[0], (uint32_t)(t + 256)); atomicMax(&smm[1], (uint32_t)(t + 256)); }
    __syncthreads();
    float gmin = (float)smm[0] * (1.0f / (float)FB);         // left edge of first nonempty fine bin
    float gmax = (float)(smm[1] + 1u) * (1.0f / (float)FB);  // right edge of last nonempty fine bin
    float inv_dw = 256.0f / (gmax - gmin);
#pragma unroll
    for (int jj = 0; jj < 2; ++jj) {
        int j = t + jj * 256;
        uint32_t cnt = sf[j];
        if (cnt) {
            float c = ((float)j + 0.5f) * (1.0f / (float)FB);  // fine-bin center
            int q = (int)((c - gmin) * inv_dw);
            q = q < 0 ? 0 : (q > 255 ? 255 : q);
            atomicAdd(&sc[q], cnt);
        }
    }
    __syncthreads();
    // inclusive integer scan -> cdf
#pragma unroll
    for (int d = 1; d < 256; d <<= 1) {
        uint32_t v = (t >= d) ? sc[t - d] : 0u;
        __syncthreads();
        sc[t] += v;
        __syncthreads();
    }
    float* cf = (float*)ctl;
    cf[t] = (float)((double)sc[t] * (1.0 / (double)HW));  // overwrite hist[0..255] with cdf
    if (t == 0) { cf[256] = gmin; cf[257] = gmax; }
}

// ---------------- K3: fused main pass + finalize ----------------
__device__ __forceinline__ void px(float r0, float r1, float r2,
                                   float i0, float i1, float i2, float l,
                                   float& rgp, float& lp,
                                   const float* __restrict__ scdf, float gmin, float inv_dw,
                                   float& a0, float& a1, float& a2,
                                   float& a3, float& a4, float& a5) {
    a0 += fabsf(r0 * l - i0) + fabsf(r1 * l - i1) + fabsf(r2 * l - i2);
    float rmax = fmaxf(r0, fmaxf(r1, r2));
    float imax = fmaxf(i0, fmaxf(i1, i2));
    float t = (imax - gmin) * inv_dw;
    t = fmaxf(t, 0.f);
    int bi = (int)t;
    float eq;
    if (bi >= 255) eq = scdf[255];
    else {
        float fr = t - (float)bi;
        eq = scdf[bi] + fr * (scdf[bi + 1] - scdf[bi]);
    }
    a1 += fabsf(rmax - eq);
    float rg = gray_pil(r0, r1, r2);
    a3 += rg;
    a5 += l * __expf(-10.f * rg);
    float drg = fabsf(rg - rgp);
    a2 += drg;
    a4 += fabsf(l - lp) * __expf(-10.f * drg);
    rgp = rg;
    lp = l;
}

// 512 blocks x 16 waves. Each block = 4-row tile;
// thread t: columns (t&511)*4..+3, rows h0..h0+1 where h0 = bid*4 + (t>>9)*2.
// Prologue reloads the previous row's R,L for the vertical-diff carry (tile redundancy 4/(7*2)).
__global__ __launch_bounds__(1024, 4)
void main_k(const float* __restrict__ im, const float* __restrict__ R,
            const float* __restrict__ L, uint32_t* __restrict__ ctl,
            float* __restrict__ out) {
    __shared__ float scdf[256];
    __shared__ float red[6][16];
    int t = threadIdx.x;

    const float* cf = (const float*)ctl;
    if (t < 256) scdf[t] = cf[t];
    float gmin = cf[256];
    float gmax = cf[257];
    float inv_dw = 256.0f / (gmax - gmin);
    __syncthreads();

    int w = (t & 511) * 4;                    // 4 adjacent columns per thread
    int h0 = blockIdx.x * 4 + ((t >> 9) * 2); // 2-row strip per thread

    float a0 = 0.f, a1 = 0.f, a2 = 0.f, a3 = 0.f, a4 = 0.f, a5 = 0.f;
    float rgp[4], lp[4];
    if (h0 > 0) {
        int p = (h0 - 1) * WW + w;
        float4 Ra = *(const float4*)(R + p);
        float4 Rb = *(const float4*)(R + p + HW);
        float4 Rc = *(const float4*)(R + p + 2 * HW);
        float4 Lv = *(const float4*)(L + p);
        rgp[0] = gray_pil(Ra.x, Rb.x, Rc.x); lp[0] = Lv.x;
        rgp[1] = gray_pil(Ra.y, Rb.y, Rc.y); lp[1] = Lv.y;
        rgp[2] = gray_pil(Ra.z, Rb.z, Rc.z); lp[2] = Lv.z;
        rgp[3] = gray_pil(Ra.w, Rb.w, Rc.w); lp[3] = Lv.w;
    } else {
        rgp[0] = rgp[1] = rgp[2] = rgp[3] = 0.f;
        lp[0] = lp[1] = lp[2] = lp[3] = 0.f;
    }

#pragma unroll
    for (int h = h0; h < h0 + 2; ++h) {
        int p = h * WW + w;
        float4 r0 = *(const float4*)(R + p);
        float4 r1 = *(const float4*)(R + p + HW);
        float4 r2 = *(const float4*)(R + p + 2 * HW);
        float4 i0 = *(const float4*)(im + p);
        float4 i1 = *(const float4*)(im + p + HW);
        float4 i2 = *(const float4*)(im + p + 2 * HW);
        float4 lv = *(const float4*)(L + p);
        px(r0.x, r1.x, r2.x, i0.x, i1.x, i2.x, lv.x, rgp[0], lp[0], scdf, gmin, inv_dw, a0, a1, a2, a3, a4, a5);
        px(r0.y, r1.y, r2.y, i0.y, i1.y, i2.y, lv.y, rgp[1], lp[1], scdf, gmin, inv_dw, a0, a1, a2, a3, a4, a5);
        px(r0.z, r1.z, r2.z, i0.z, i1.z, i2.z, lv.z, rgp[2], lp[2], scdf, gmin, inv_dw, a0, a1, a2, a3, a4, a5);
        px(r0.w, r1.w, r2.w, i0.w, i1.w, i2.w, lv.w, rgp[3], lp[3], scdf, gmin, inv_dw, a0, a1, a2, a3, a4, a5);
    }
    if (h0 + 2 == HH) {  // boundary at h = 2048: |0 - x[2047]|
#pragma unroll
        for (int j = 0; j < 4; ++j) {
            a2 += rgp[j];
            a4 += lp[j] * __expf(-10.f * rgp[j]);
        }
    }

    for (int off = 32; off; off >>= 1) {
        a0 += __shfl_down(a0, off);
        a1 += __shfl_down(a1, off);
        a2 += __shfl_down(a2, off);
        a3 += __shfl_down(a3, off);
        a4 += __shfl_down(a4, off);
        a5 += __shfl_down(a5, off);
    }
    int lane = t & 63, wv = t >> 6;
    if (lane == 0) {
        red[0][wv] = a0; red[1][wv] = a1; red[2][wv] = a2;
        red[3][wv] = a3; red[4][wv] = a4; red[5][wv] = a5;
    }
    __syncthreads();
    if (t == 0) {
        float s0 = 0, s1 = 0, s2 = 0, s3 = 0, s4 = 0, s5 = 0;
        for (int k = 0; k < 16; k++) {
            s0 += red[0][k]; s1 += red[1][k]; s2 += red[2][k];
            s3 += red[3][k]; s4 += red[4][k]; s5 += red[5][k];
        }
        float* acc = (float*)(ctl + 512);
        atomicAdd(&acc[0], s0);
        atomicAdd(&acc[1], s1);
        atomicAdd(&acc[2], s2);
        atomicAdd(&acc[3], s3);
        atomicAdd(&acc[4], s4);
        atomicAdd(&acc[5], s5);
        __threadfence();
        uint32_t old = atomicAdd(&ctl[518], 1u);
        if (old == G3 - 1) {  // last block: all acc atomics happened-before
            float v0 = atomicAdd(&acc[0], 0.f);
            float v1 = atomicAdd(&acc[1], 0.f);
            float v2 = atomicAdd(&acc[2], 0.f);
            float v3 = atomicAdd(&acc[3], 0.f);
            float v4 = atomicAdd(&acc[4], 0.f);
            float v5 = atomicAdd(&acc[5], 0.f);
            float recon_low = v0 / (3.0f * (float)HW);
            float recon_eq = v1 / (float)HW;
            float denom = 2.0f * 2049.0f * 2050.0f;
            float r_smooth = (v2 + 2.f * v3) / denom;
            float ismooth = (v4 + 2.f * v5) / denom;
            out[0] = recon_low + 0.1f * ismooth + 0.1f * recon_eq + 0.01f * r_smooth;
        }
    }
}

extern "C" void kernel_launch(void* const* d_in, const int* in_sizes, int n_in,
                              void* d_out, int out_size, void* d_ws, size_t ws_size,
                              hipStream_t stream) {
    const float* im = (const float*)d_in[0];
    const float* R = (const float*)d_in[1];
    const float* L = (const float*)d_in[2];
    float* out = (float*)d_out;
    uint32_t* ctl = (uint32_t*)d_ws;

    hipMemsetAsync(d_ws, 0, 519 * 4, stream);  // graph-capturable memset node
    hipLaunchKernelGGL(hist_k, dim3(G1), dim3(1024), 0, stream, im, ctl);
    hipLaunchKernelGGL(cdf_k, dim3(1), dim3(256), 0, stream, ctl);
    hipLaunchKernelGGL(main_k, dim3(G3), dim3(1024), 0, stream, im, R, L, ctl, out);
}